// Round 10
// baseline (114.779 us; speedup 1.0000x reference)
//
#include <hip/hip_runtime.h>
#include <cstdint>

// ---------------------------------------------------------------------------
// H3 block: out = q * S4D( v * Shift(k) ),  q/k/v = W{q,k,v} @ x + b
// prep   : transpose x -> (b,l,d) f16  |  convert W -> f16   (concurrent)
// gemm   : merged M=1536 x N=16384 x K=512, 128x128, BK=64, gload_lds(16B),
//          swizzled ds_read_b128, LDS epilogue -> coalesced half8 stores
// s4d    : one block per (b,h) (4096 blocks, ~46KB LDS -> 3/CU resident);
//          tables built IN-BLOCK: T1,T2,V in prologue; E kept in 16 regs and
//          stored after the shift phase (reuses T1 buffer); T from Kt.
//          5 barriers total, serial scan overlapped via 3-block TLP.
// Swizzle: within a 64-half row R, 16B slot s -> s ^ (R&7).
// ---------------------------------------------------------------------------

#define DMODEL 512
#define LSEQ 2048

typedef _Float16 half_t;
typedef __attribute__((ext_vector_type(2))) _Float16 half2v;
typedef __attribute__((ext_vector_type(4))) _Float16 half4v;
typedef __attribute__((ext_vector_type(8))) _Float16 half8v;
typedef __attribute__((ext_vector_type(4))) float floatx4;

#define SW(R, c) ((R) * 64 + ((((c) >> 3) ^ ((R) & 7)) << 3) + ((c) & 7))

__device__ __forceinline__ void gload_lds16(const half_t* g, half_t* l) {
  __builtin_amdgcn_global_load_lds(
      (const __attribute__((address_space(1))) uint32_t*)g,
      (__attribute__((address_space(3))) uint32_t*)l, 16, 0, 0);
}

#define WAIT_LGKM_BAR()                                   \
  do {                                                    \
    asm volatile("s_waitcnt lgkmcnt(0)" ::: "memory");    \
    __builtin_amdgcn_s_barrier();                         \
    __builtin_amdgcn_sched_barrier(0);                    \
  } while (0)

// ---------------- prep: transpose x | convert W ----------------------------
__global__ __launch_bounds__(256) void prep(
    const float* __restrict__ x, const float* __restrict__ Wq,
    const float* __restrict__ Wk, const float* __restrict__ Wv,
    half_t* __restrict__ xT, half_t* __restrict__ W16) {
  __shared__ float tile[64][68];
  int bid = blockIdx.x;
  int tid = threadIdx.x;
  if (bid < 2048) {
    int b = bid >> 8, rem = bid & 255;
    int d0 = (rem >> 5) * 64, l0 = (rem & 31) * 64;
    int dy = tid >> 4, lx = tid & 15;
    const float* xp = x + ((size_t)(b * 512 + d0)) * 2048 + l0;
#pragma unroll
    for (int rr = 0; rr < 4; rr++) {
      float4 v = *(const float4*)(xp + (size_t)(rr * 16 + dy) * 2048 + lx * 4);
      *(float4*)&tile[rr * 16 + dy][lx * 4] = v;
    }
    __syncthreads();
    half_t* op = xT + ((size_t)(b * 2048 + l0)) * 512 + d0;
    int lr = tid >> 2, c4 = tid & 3;
#pragma unroll
    for (int cc = 0; cc < 2; cc++) {
      int ch = cc * 4 + c4;
      half8v hv;
#pragma unroll
      for (int e = 0; e < 8; e++) hv[e] = (half_t)tile[ch * 8 + e][lr];
      *(half8v*)(op + (size_t)lr * 512 + ch * 8) = hv;
    }
  } else {
    int base = (bid - 2048) * 256 + tid;
#pragma unroll
    for (int it = 0; it < 6; it++) {
      int i = base + it * 131072;
      const float* src = (i < 262144) ? Wq : ((i < 524288) ? Wk : Wv);
      W16[i] = (half_t)src[i & 262143];
    }
  }
}

// ---------------- merged qkv GEMM (128x128, BK=64, LDS epilogue) -----------
__global__ __launch_bounds__(256) void gemm_qkv(
    const half_t* __restrict__ xT, const half_t* __restrict__ Wstk,
    const float* __restrict__ bq, const float* __restrict__ bk,
    const float* __restrict__ bv, half_t* __restrict__ outq,
    half_t* __restrict__ outk, half_t* __restrict__ outv) {
  __shared__ half_t smem[16384];   // As 8192 | Bs 8192; reused as C 128x128
  half_t* As = smem;
  half_t* Bs = smem + 8192;
  int flat = blockIdx.x;                         // 1536 = 8 xcd x 192
  int swz = (flat & 7) * 192 + (flat >> 3);      // XCD chunk swizzle
  int nt = swz / 12, mt = swz - nt * 12;
  int n0 = nt * 128, m0 = mt * 128;
  int tid = threadIdx.x;
  int lane = tid & 63, wid = tid >> 6;
  int wr = wid >> 1, wc = wid & 1;
  int lrow = lane & 15, lg = lane >> 4;
  int rsub = lane >> 3, ssub = lane & 7;
  int gslot = ssub ^ rsub;                       // inverse-swizzled source slot

  floatx4 acc[4][4];
#pragma unroll
  for (int i = 0; i < 4; i++)
#pragma unroll
    for (int j = 0; j < 4; j++) acc[i][j] = (floatx4){0.f, 0.f, 0.f, 0.f};

  const half_t* gA = Wstk + (size_t)(m0 + wid * 32 + rsub) * 512 + gslot * 8;
  const half_t* gB = xT + (size_t)(n0 + wid * 32 + rsub) * 512 + gslot * 8;

  for (int kk = 0; kk < 512; kk += 64) {
#pragma unroll
    for (int i = 0; i < 4; i++) {
      int c = wid * 4 + i;                       // 1KB chunk, rows c*8..c*8+7
      gload_lds16(gA + (size_t)i * 8 * 512 + kk, As + c * 512);
      gload_lds16(gB + (size_t)i * 8 * 512 + kk, Bs + c * 512);
    }
    __syncthreads();
#pragma unroll
    for (int h = 0; h < 2; h++) {
      half8v af[4], bf[4];
#pragma unroll
      for (int i = 0; i < 4; i++) {
        int r = wr * 64 + i * 16 + lrow;
        af[i] = *(const half8v*)(As + r * 64 + ((h * 4 + lg) ^ (r & 7)) * 8);
      }
#pragma unroll
      for (int j = 0; j < 4; j++) {
        int r = wc * 64 + j * 16 + lrow;
        bf[j] = *(const half8v*)(Bs + r * 64 + ((h * 4 + lg) ^ (r & 7)) * 8);
      }
#pragma unroll
      for (int i = 0; i < 4; i++)
#pragma unroll
        for (int j = 0; j < 4; j++)
          acc[i][j] = __builtin_amdgcn_mfma_f32_16x16x32_f16(af[i], bf[j],
                                                             acc[i][j], 0, 0, 0);
    }
    __syncthreads();
  }

  // ---- epilogue via LDS: frags -> swizzled C tile -> coalesced stores ----
  int z = m0 >> 9;                               // uniform per block
  const float* bias = (z == 0) ? bq : ((z == 1) ? bk : bv);
  half_t* smemC = smem;                          // 128 x 128 halfs, slot^=(d&15)
#pragma unroll
  for (int i = 0; i < 4; i++) {
    int dl = wr * 64 + i * 16 + 4 * lg;
    float4 b4 = *(const float4*)&bias[(m0 + dl) & 511];
#pragma unroll
    for (int j = 0; j < 4; j++) {
      int ll = wc * 64 + j * 16 + lrow;
#pragma unroll
      for (int reg = 0; reg < 4; reg++) {
        int d = dl + reg;
        float val = acc[i][j][reg] + ((const float*)&b4)[reg];
        smemC[d * 128 + (((ll >> 3) ^ (d & 15)) << 3) + (ll & 7)] = (half_t)val;
      }
    }
  }
  __syncthreads();
  {
    int t4 = tid >> 4, ch = tid & 15;
    int b = n0 >> 11, l0 = n0 & 2047;
    half_t* outp = (z == 0) ? outq : ((z == 1) ? outk : outv);
#pragma unroll
    for (int rep = 0; rep < 8; rep++) {
      int d = rep * 16 + t4;
      half8v v = *(const half8v*)(smemC + d * 128 + ((ch ^ (d & 15)) << 3));
      size_t rowb = ((size_t)(b * 512 + ((m0 + d) & 511))) * 2048;
      if (z == 0) {
        *(half8v*)(outp + rowb + l0 + ch * 8) = v;       // q: linear
      } else {                                            // k,v: swizzled image
        int j = (l0 >> 6) + (ch >> 3);
        int s = ch & 7;
        *(half8v*)(outp + rowb + j * 64 + ((s ^ (j & 7)) << 3)) = v;
      }
    }
  }
}

// ---------------- fused Shift + S4D, one block per (b,h) -------------------
__global__ __launch_bounds__(256) void s4d_main(
    const half_t* __restrict__ kimg, const half_t* __restrict__ vimg,
    const float* __restrict__ shC, const float* __restrict__ log_dt,
    const float* __restrict__ A_real, const float* __restrict__ A_imag,
    const float* __restrict__ C_re, const float* __restrict__ C_im,
    const float* __restrict__ shD, const float* __restrict__ s4D,
    const half_t* __restrict__ qbuf, float* __restrict__ outp) {
  __shared__ half_t kl[33 * 64];   // row 0 zeros; row 1+j = k chunk j
  __shared__ half_t vg[32 * 64];   // v, later G~ (f16)
  __shared__ half_t uh[32 * 64];   // u = v * shift(k)
  __shared__ half_t tabA[4096];    // T1 -> E
  __shared__ half_t tabB[4096];    // T2 -> T
  __shared__ half_t tabC[4096];    // V
  __shared__ float SG[32 * 66];    // S states / flat y
  __shared__ float scr[384];       // Kt[64] tapl[64] aL bL wrL wiL crL ciL wT[64]
  int bh = blockIdx.x;
  int h = bh & 511;
  int tid = threadIdx.x;
  int lane = tid & 63, wid = tid >> 6;
  int lrow = lane & 15, lg = lane >> 4;
  int mi = wid & 1, ri0 = wid >> 1;

  float* Kt   = scr;
  float* tapl = scr + 64;
  float* aL   = scr + 128;
  float* bL   = scr + 160;
  float* wrL  = scr + 192;
  float* wiL  = scr + 224;
  float* crL  = scr + 256;
  float* ciL  = scr + 288;
  float* wTL  = scr + 320;   // interleaved re/im [64]

  // ---- issue k/v gloads first (latency hides under table build) ----
  gload_lds16(kimg + (size_t)bh * 2048 + wid * 512 + lane * 8,
              kl + 64 + wid * 512);
  gload_lds16(vimg + (size_t)bh * 2048 + wid * 512 + lane * 8,
              vg + wid * 512);
  if (tid < 8) {
    half8v zz = {(_Float16)0, (_Float16)0, (_Float16)0, (_Float16)0,
                 (_Float16)0, (_Float16)0, (_Float16)0, (_Float16)0};
    *(half8v*)(kl + tid * 8) = zz;
  }
  if (tid < 64) { Kt[tid] = 0.f; tapl[tid] = shC[h * 64 + tid]; }
  if (tid < 32) {
    int n = tid, hn = h * 32 + n;
    float dt = expf(log_dt[h]);
    float Ar = -expf(A_real[hn]), Ai = A_imag[hn];
    float a = dt * Ar, b = dt * Ai;
    float ea = expf(a);
    float wr = ea * cosf(b), wi = ea * sinf(b);
    float Am2 = Ar * Ar + Ai * Ai;
    float zr = wr - 1.0f, zi = wi;
    float qr = (zr * Ar + zi * Ai) / Am2;
    float qi = (zi * Ar - zr * Ai) / Am2;
    aL[n] = a; bL[n] = b; wrL[n] = wr; wiL[n] = wi;
    crL[n] = C_re[hn] * qr - C_im[hn] * qi;
    ciL[n] = C_re[hn] * qi + C_im[hn] * qr;
    float e64 = expf(64.f * a);
    wTL[2 * n]     = e64 * cosf(64.f * b);
    wTL[2 * n + 1] = e64 * sinf(64.f * b);
  }
  __syncthreads();

  // ---- w^r loop: V -> tabC, Kt sums, E kept in registers ----
  half_t eR[8], eI[8];
  {
    int r = tid >> 2, nb = (tid & 3) * 8;
    float ksum = 0.f;
#pragma unroll
    for (int i = 0; i < 8; i++) {
      int n = nb + i;
      float a = aL[n], b = bL[n];
      float cr = crL[n], ci = ciL[n];
      float er = expf(a * (float)r);
      float w0r = er * cosf(b * (float)r), w0i = er * sinf(b * (float)r);
      ksum += 2.f * (cr * w0r - ci * w0i);
      float wr = wrL[n], wi = wiL[n];
      float w1r = w0r * wr - w0i * wi, w1i = w0r * wi + w0i * wr;
      eR[i] = (half_t)(2.f * (cr * w1r - ci * w1i));
      eI[i] = (half_t)(-2.f * (cr * w1i + ci * w1r));
      tabC[SW(2 * n, 63 - r)]     = (half_t)w0r;
      tabC[SW(2 * n + 1, 63 - r)] = (half_t)w0i;
    }
    atomicAdd(&Kt[r], ksum);
  }
  // ---- T1, T2 from taps ----
#pragma unroll
  for (int e = 0; e < 16; e++) {
    int idx = e * 256 + tid;
    int r = idx >> 6, t = idx & 63;
    int d = r - t;
    int a = SW(r, t);
    tabA[a] = (d >= 0) ? (half_t)tapl[d] : (half_t)0.f;
    tabB[a] = (d < 0) ? (half_t)tapl[64 + d] : (half_t)0.f;
  }
  float sDsh = shD[h];
  float sD4 = s4D[h];
  float wTr = wTL[2 * (tid & 31)], wTi = wTL[2 * (tid & 31) + 1];
  asm volatile("s_waitcnt vmcnt(0) lgkmcnt(0)" ::: "memory");
  __builtin_amdgcn_s_barrier();
  __builtin_amdgcn_sched_barrier(0);

#define LDF(base, r, ks, key) \
  (*(const half8v*)((base) + (r) * 64 + (((ks) * 4 + lg) ^ (key)) * 8))

  floatx4 acc[2];
  // ---- shift: shift[j][r] = k_j @ T1' + k_{j-1} @ T2' ----
  acc[0] = (floatx4){0.f, 0.f, 0.f, 0.f};
  acc[1] = (floatx4){0.f, 0.f, 0.f, 0.f};
  {
    int jA = mi * 16 + lrow;
    int key1 = lrow & 7, key2 = (lrow + 7) & 7;
#pragma unroll
    for (int ks = 0; ks < 2; ks++) {
      half8v a1 = LDF(kl, 1 + jA, ks, key1);
      half8v a2 = LDF(kl, jA, ks, key2);
#pragma unroll
      for (int tt = 0; tt < 2; tt++) {
        int rb = (ri0 + tt * 2) * 16 + lrow;
        half8v b1 = LDF(tabA, rb, ks, lrow & 7);
        half8v b2 = LDF(tabB, rb, ks, lrow & 7);
        acc[tt] = __builtin_amdgcn_mfma_f32_16x16x32_f16(a1, b1, acc[tt], 0, 0, 0);
        acc[tt] = __builtin_amdgcn_mfma_f32_16x16x32_f16(a2, b2, acc[tt], 0, 0, 0);
      }
    }
  }
  // u = v * (shift + shD*k)
#pragma unroll
  for (int tt = 0; tt < 2; tt++) {
#pragma unroll
    for (int reg = 0; reg < 4; reg++) {
      int j = mi * 16 + 4 * lg + reg;
      int r = (ri0 + tt * 2) * 16 + lrow;
      int cph = (((r >> 3) ^ (j & 7)) << 3) + (r & 7);
      float kvv = (float)kl[(1 + j) * 64 + cph];
      float vvv = (float)vg[j * 64 + cph];
      uh[j * 64 + cph] = (half_t)(vvv * (acc[tt][reg] + sDsh * kvv));
    }
  }
  WAIT_LGKM_BAR();

  // ---- S phase (u @ V); concurrently store E (regs->tabA), T (Kt->tabB) --
  {
    int r = tid >> 2, nb = (tid & 3) * 8;
#pragma unroll
    for (int i = 0; i < 8; i++) {
      int n = nb + i;
      tabA[SW(r, 2 * n)]     = eR[i];
      tabA[SW(r, 2 * n + 1)] = eI[i];
    }
  }
#pragma unroll
  for (int e = 0; e < 16; e++) {
    int idx = e * 256 + tid;
    int r = idx >> 6, t = idx & 63;
    int d = r - t;
    tabB[SW(r, t)] = (d >= 0) ? (half_t)Kt[d] : (half_t)0.f;
  }
  acc[0] = (floatx4){0.f, 0.f, 0.f, 0.f};
  acc[1] = (floatx4){0.f, 0.f, 0.f, 0.f};
#pragma unroll
  for (int ks = 0; ks < 2; ks++) {
    half8v a = LDF(uh, mi * 16 + lrow, ks, lrow & 7);
#pragma unroll
    for (int tt = 0; tt < 2; tt++) {
      int rb = (ri0 + tt * 2) * 16 + lrow;
      half8v b = LDF(tabC, rb, ks, lrow & 7);
      acc[tt] = __builtin_amdgcn_mfma_f32_16x16x32_f16(a, b, acc[tt], 0, 0, 0);
    }
  }
#pragma unroll
  for (int tt = 0; tt < 2; tt++) {
    int ri = ri0 + tt * 2;
#pragma unroll
    for (int reg = 0; reg < 4; reg++) {
      int j = mi * 16 + 4 * lg + reg;
      SG[j * 66 + ri * 16 + lrow] = acc[tt][reg];
    }
  }
  WAIT_LGKM_BAR();

  // ---- scan (thread n): emit f16 G_{j-1} directly into vg ----
  if (tid < 32) {
    int n = tid;
    float gr = 0.f, gi = 0.f;
#pragma unroll 4
    for (int j = 0; j < 32; j++) {
      float tr = SG[j * 66 + 2 * n], ti = SG[j * 66 + 2 * n + 1];
      half2v gp = {(half_t)gr, (half_t)gi};
      *(half2v*)(vg + j * 64 + (((n >> 2) ^ (j & 7)) << 3) + 2 * (n & 3)) = gp;
      float nr = wTr * gr - wTi * gi + tr;
      gi = wTr * gi + wTi * gr + ti;
      gr = nr;
    }
  }
  WAIT_LGKM_BAR();

  // ---- Y: Y[j][r] = G~_j @ E' + u_j @ T' ; y -> SG flat ----
  acc[0] = (floatx4){0.f, 0.f, 0.f, 0.f};
  acc[1] = (floatx4){0.f, 0.f, 0.f, 0.f};
#pragma unroll
  for (int ks = 0; ks < 2; ks++) {
    half8v ag = LDF(vg, mi * 16 + lrow, ks, lrow & 7);
    half8v au = LDF(uh, mi * 16 + lrow, ks, lrow & 7);
#pragma unroll
    for (int tt = 0; tt < 2; tt++) {
      int rb = (ri0 + tt * 2) * 16 + lrow;
      half8v be = LDF(tabA, rb, ks, lrow & 7);
      half8v bt = LDF(tabB, rb, ks, lrow & 7);
      acc[tt] = __builtin_amdgcn_mfma_f32_16x16x32_f16(ag, be, acc[tt], 0, 0, 0);
      acc[tt] = __builtin_amdgcn_mfma_f32_16x16x32_f16(au, bt, acc[tt], 0, 0, 0);
    }
  }
#pragma unroll
  for (int tt = 0; tt < 2; tt++) {
#pragma unroll
    for (int reg = 0; reg < 4; reg++) {
      int j = mi * 16 + 4 * lg + reg;
      int r = (ri0 + tt * 2) * 16 + lrow;
      int cph = (((r >> 3) ^ (j & 7)) << 3) + (r & 7);
      SG[j * 64 + r] = acc[tt][reg] + sD4 * (float)uh[j * 64 + cph];
    }
  }
  WAIT_LGKM_BAR();

  // ---- final coalesced pass: out = q * y ----
  {
    size_t base = (size_t)bh * 2048;
    half8v qv = *(const half8v*)(qbuf + base + tid * 8);
    float* op = outp + base;
    float4 o0, o1;
    o0.x = (float)qv[0] * SG[tid * 8 + 0];
    o0.y = (float)qv[1] * SG[tid * 8 + 1];
    o0.z = (float)qv[2] * SG[tid * 8 + 2];
    o0.w = (float)qv[3] * SG[tid * 8 + 3];
    o1.x = (float)qv[4] * SG[tid * 8 + 4];
    o1.y = (float)qv[5] * SG[tid * 8 + 5];
    o1.z = (float)qv[6] * SG[tid * 8 + 6];
    o1.w = (float)qv[7] * SG[tid * 8 + 7];
    *(float4*)(op + tid * 8) = o0;
    *(float4*)(op + tid * 8 + 4) = o1;
  }
#undef LDF
}

// ---------------------------------------------------------------------------
extern "C" void kernel_launch(void* const* d_in, const int* in_sizes, int n_in,
                              void* d_out, int out_size, void* d_ws, size_t ws_size,
                              hipStream_t stream) {
  const float* x      = (const float*)d_in[0];
  const float* Wq     = (const float*)d_in[1];
  const float* bq     = (const float*)d_in[2];
  const float* Wk     = (const float*)d_in[3];
  const float* bk     = (const float*)d_in[4];
  const float* Wv     = (const float*)d_in[5];
  const float* bv     = (const float*)d_in[6];
  const float* shC    = (const float*)d_in[7];
  const float* shD    = (const float*)d_in[8];
  const float* log_dt = (const float*)d_in[9];
  const float* A_real = (const float*)d_in[10];
  const float* A_imag = (const float*)d_in[11];
  const float* C_re   = (const float*)d_in[12];
  const float* C_im   = (const float*)d_in[13];
  const float* s4D    = (const float*)d_in[14];
  float* out = (float*)d_out;
  half_t* wsh = (half_t*)d_ws;

  half_t* qbuf = wsh;                         // 8388608 halfs (linear)
  half_t* kbuf = wsh + 8388608;               // 8388608 (swizzled image)
  half_t* vbuf = wsh + 16777216;              // 8388608 (swizzled image)
  half_t* xT16 = wsh + 25165824;              // 8388608
  half_t* W16  = wsh + 33554432;              // 786432

  prep<<<2560, 256, 0, stream>>>(x, Wq, Wk, Wv, xT16, W16);
  gemm_qkv<<<dim3(1536), 256, 0, stream>>>(xT16, W16, bq, bk, bv,
                                           qbuf, kbuf, vbuf);
  s4d_main<<<4096, 256, 0, stream>>>(kbuf, vbuf, shC, log_dt, A_real, A_imag,
                                     C_re, C_im, shD, s4D, qbuf, out);
}

// Round 11
// 85.379 us; speedup vs baseline: 1.3443x; 1.3443x over previous
//
#include <hip/hip_runtime.h>
#include <cstdint>

// ---------------------------------------------------------------------------
// H3 block: out = q * S4D( v * Shift(k) ),  q/k/v = W{q,k,v} @ x + b
// prep   : ONE kernel, 3 concurrent sections (tables | transpose | convert)
// gemm   : merged M=1536 x N=16384 x K=512, 128x128, BK=64, gload_lds(16B),
//          swizzled ds_read_b128, LDS epilogue -> coalesced half8 stores
// s4d    : one block per (b,h), 4096 blocks, 45 KB LDS -> 3 blocks/CU.
//          3 table buffers: T1,T2,V staged in prologue; E,T staged (global,
//          prep-built) into the same buffers DURING the S phase (raw barriers
//          + counted waits keep the overlap alive). XCD swizzle gives each
//          XCD a contiguous head range so table re-reads are L2-hits.
// Swizzle: within a 64-half row R, 16B slot s -> s ^ (R&7).
// ---------------------------------------------------------------------------

#define DMODEL 512
#define LSEQ 2048

typedef _Float16 half_t;
typedef __attribute__((ext_vector_type(2))) _Float16 half2v;
typedef __attribute__((ext_vector_type(4))) _Float16 half4v;
typedef __attribute__((ext_vector_type(8))) _Float16 half8v;
typedef __attribute__((ext_vector_type(4))) float floatx4;

#define SW(R, c) ((R) * 64 + ((((c) >> 3) ^ ((R) & 7)) << 3) + ((c) & 7))

__device__ __forceinline__ void gload_lds16(const half_t* g, half_t* l) {
  __builtin_amdgcn_global_load_lds(
      (const __attribute__((address_space(1))) uint32_t*)g,
      (__attribute__((address_space(3))) uint32_t*)l, 16, 0, 0);
}

#define WAIT_LGKM_BAR()                                   \
  do {                                                    \
    asm volatile("s_waitcnt lgkmcnt(0)" ::: "memory");    \
    __builtin_amdgcn_s_barrier();                         \
    __builtin_amdgcn_sched_barrier(0);                    \
  } while (0)

// ---------------- merged prep: tables | transpose | convert ---------------
__global__ __launch_bounds__(256) void prep(
    const float* __restrict__ x, const float* __restrict__ Wq,
    const float* __restrict__ Wk, const float* __restrict__ Wv,
    const float* __restrict__ log_dt, const float* __restrict__ A_real,
    const float* __restrict__ A_imag, const float* __restrict__ C_re,
    const float* __restrict__ C_im, const float* __restrict__ shC,
    half_t* __restrict__ xT, half_t* __restrict__ W16,
    half_t* __restrict__ Vt, half_t* __restrict__ Et, half_t* __restrict__ Tt,
    half_t* __restrict__ T1t, half_t* __restrict__ T2t,
    float* __restrict__ wt2) {
  __shared__ float tile[64][68];                 // transpose section
  __shared__ float aL[32], bL[32], wrL[32], wiL[32], crL[32], ciL[32];
  __shared__ float Kt[64], tapl[64];
  int bid = blockIdx.x;
  int tid = threadIdx.x;

  if (bid < 512) {
    // ---------------- s4d tables for head h = bid ----------------
    int h = bid;
    if (tid < 64) { Kt[tid] = 0.f; tapl[tid] = shC[h * 64 + tid]; }
    if (tid < 32) {
      int n = tid, hn = h * 32 + n;
      float dt = expf(log_dt[h]);
      float Ar = -expf(A_real[hn]), Ai = A_imag[hn];
      float a = dt * Ar, b = dt * Ai;
      float ea = expf(a);
      float wr = ea * cosf(b), wi = ea * sinf(b);
      float Am2 = Ar * Ar + Ai * Ai;
      float zr = wr - 1.0f, zi = wi;
      float qr = (zr * Ar + zi * Ai) / Am2;
      float qi = (zi * Ar - zr * Ai) / Am2;
      aL[n] = a; bL[n] = b; wrL[n] = wr; wiL[n] = wi;
      crL[n] = C_re[hn] * qr - C_im[hn] * qi;
      ciL[n] = C_re[hn] * qi + C_im[hn] * qr;
      float e64 = expf(64.0f * a);
      wt2[h * 64 + 2 * n]     = e64 * cosf(64.0f * b);
      wt2[h * 64 + 2 * n + 1] = e64 * sinf(64.0f * b);
    }
    __syncthreads();
    size_t base = (size_t)h * 4096;
    {
      int r = tid >> 2;
      int nb = (tid & 3) * 8;
      float ksum = 0.f;
#pragma unroll
      for (int i = 0; i < 8; i++) {
        int n = nb + i;
        float a = aL[n], b = bL[n];
        float cr = crL[n], ci = ciL[n];
        float er = expf(a * (float)r);
        float w0r = er * cosf(b * (float)r), w0i = er * sinf(b * (float)r);
        ksum += 2.f * (cr * w0r - ci * w0i);
        float wr = wrL[n], wi = wiL[n];
        float w1r = w0r * wr - w0i * wi, w1i = w0r * wi + w0i * wr;
        Et[base + SW(r, 2 * n)]     = (half_t)(2.f * (cr * w1r - ci * w1i));
        Et[base + SW(r, 2 * n + 1)] = (half_t)(-2.f * (cr * w1i + ci * w1r));
        Vt[base + SW(2 * n, 63 - r)]     = (half_t)w0r;
        Vt[base + SW(2 * n + 1, 63 - r)] = (half_t)w0i;
      }
      atomicAdd(&Kt[r], ksum);
    }
    __syncthreads();
#pragma unroll
    for (int e = 0; e < 16; e++) {
      int idx = e * 256 + tid;
      int r = idx >> 6, t = idx & 63;
      int d = r - t;
      size_t a = base + SW(r, t);
      Tt[a]  = (d >= 0) ? (half_t)Kt[d] : (half_t)0.f;
      T1t[a] = (d >= 0) ? (half_t)tapl[d] : (half_t)0.f;
      T2t[a] = (d < 0) ? (half_t)tapl[64 + d] : (half_t)0.f;
    }
  } else if (bid < 2560) {
    // ---------------- transpose x (64x64 tiles) ----------------
    int i = bid - 512;
    int b = i >> 8, rem = i & 255;
    int d0 = (rem >> 5) * 64, l0 = (rem & 31) * 64;
    int dy = tid >> 4, lx = tid & 15;
    const float* xp = x + ((size_t)(b * 512 + d0)) * 2048 + l0;
#pragma unroll
    for (int rr = 0; rr < 4; rr++) {
      float4 v = *(const float4*)(xp + (size_t)(rr * 16 + dy) * 2048 + lx * 4);
      *(float4*)&tile[rr * 16 + dy][lx * 4] = v;
    }
    __syncthreads();
    half_t* op = xT + ((size_t)(b * 2048 + l0)) * 512 + d0;
    int lr = tid >> 2, c4 = tid & 3;
#pragma unroll
    for (int cc = 0; cc < 2; cc++) {
      int ch = cc * 4 + c4;
      half8v hv;
#pragma unroll
      for (int e = 0; e < 8; e++) hv[e] = (half_t)tile[ch * 8 + e][lr];
      *(half8v*)(op + (size_t)lr * 512 + ch * 8) = hv;
    }
  } else {
    // ---------------- convert W (512 blocks x 6 strides) ----------------
    int base = (bid - 2560) * 256 + tid;
#pragma unroll
    for (int it = 0; it < 6; it++) {
      int i = base + it * 131072;
      const float* src = (i < 262144) ? Wq : ((i < 524288) ? Wk : Wv);
      W16[i] = (half_t)src[i & 262143];
    }
  }
}

// ---------------- merged qkv GEMM (128x128, BK=64, LDS epilogue) -----------
__global__ __launch_bounds__(256) void gemm_qkv(
    const half_t* __restrict__ xT, const half_t* __restrict__ Wstk,
    const float* __restrict__ bq, const float* __restrict__ bk,
    const float* __restrict__ bv, half_t* __restrict__ outq,
    half_t* __restrict__ outk, half_t* __restrict__ outv) {
  __shared__ half_t smem[16384];   // As 8192 | Bs 8192; reused as C 128x128
  half_t* As = smem;
  half_t* Bs = smem + 8192;
  int flat = blockIdx.x;                         // 1536 = 8 xcd x 192
  int swz = (flat & 7) * 192 + (flat >> 3);      // XCD chunk swizzle
  int nt = swz / 12, mt = swz - nt * 12;
  int n0 = nt * 128, m0 = mt * 128;
  int tid = threadIdx.x;
  int lane = tid & 63, wid = tid >> 6;
  int wr = wid >> 1, wc = wid & 1;
  int lrow = lane & 15, lg = lane >> 4;
  int rsub = lane >> 3, ssub = lane & 7;
  int gslot = ssub ^ rsub;                       // inverse-swizzled source slot

  floatx4 acc[4][4];
#pragma unroll
  for (int i = 0; i < 4; i++)
#pragma unroll
    for (int j = 0; j < 4; j++) acc[i][j] = (floatx4){0.f, 0.f, 0.f, 0.f};

  const half_t* gA = Wstk + (size_t)(m0 + wid * 32 + rsub) * 512 + gslot * 8;
  const half_t* gB = xT + (size_t)(n0 + wid * 32 + rsub) * 512 + gslot * 8;

  for (int kk = 0; kk < 512; kk += 64) {
#pragma unroll
    for (int i = 0; i < 4; i++) {
      int c = wid * 4 + i;                       // 1KB chunk, rows c*8..c*8+7
      gload_lds16(gA + (size_t)i * 8 * 512 + kk, As + c * 512);
      gload_lds16(gB + (size_t)i * 8 * 512 + kk, Bs + c * 512);
    }
    __syncthreads();
#pragma unroll
    for (int h = 0; h < 2; h++) {
      half8v af[4], bf[4];
#pragma unroll
      for (int i = 0; i < 4; i++) {
        int r = wr * 64 + i * 16 + lrow;
        af[i] = *(const half8v*)(As + r * 64 + ((h * 4 + lg) ^ (r & 7)) * 8);
      }
#pragma unroll
      for (int j = 0; j < 4; j++) {
        int r = wc * 64 + j * 16 + lrow;
        bf[j] = *(const half8v*)(Bs + r * 64 + ((h * 4 + lg) ^ (r & 7)) * 8);
      }
#pragma unroll
      for (int i = 0; i < 4; i++)
#pragma unroll
        for (int j = 0; j < 4; j++)
          acc[i][j] = __builtin_amdgcn_mfma_f32_16x16x32_f16(af[i], bf[j],
                                                             acc[i][j], 0, 0, 0);
    }
    __syncthreads();
  }

  // ---- epilogue via LDS: frags -> swizzled C tile -> coalesced stores ----
  int z = m0 >> 9;                               // uniform per block
  const float* bias = (z == 0) ? bq : ((z == 1) ? bk : bv);
  half_t* smemC = smem;                          // 128 x 128 halfs, slot^=(d&15)
#pragma unroll
  for (int i = 0; i < 4; i++) {
    int dl = wr * 64 + i * 16 + 4 * lg;
    float4 b4 = *(const float4*)&bias[(m0 + dl) & 511];
#pragma unroll
    for (int j = 0; j < 4; j++) {
      int ll = wc * 64 + j * 16 + lrow;
#pragma unroll
      for (int reg = 0; reg < 4; reg++) {
        int d = dl + reg;
        float val = acc[i][j][reg] + ((const float*)&b4)[reg];
        smemC[d * 128 + (((ll >> 3) ^ (d & 15)) << 3) + (ll & 7)] = (half_t)val;
      }
    }
  }
  __syncthreads();
  {
    int t4 = tid >> 4, ch = tid & 15;
    int b = n0 >> 11, l0 = n0 & 2047;
    half_t* outp = (z == 0) ? outq : ((z == 1) ? outk : outv);
#pragma unroll
    for (int rep = 0; rep < 8; rep++) {
      int d = rep * 16 + t4;
      half8v v = *(const half8v*)(smemC + d * 128 + ((ch ^ (d & 15)) << 3));
      size_t rowb = ((size_t)(b * 512 + ((m0 + d) & 511))) * 2048;
      if (z == 0) {
        *(half8v*)(outp + rowb + l0 + ch * 8) = v;       // q: linear
      } else {                                            // k,v: swizzled image
        int j = (l0 >> 6) + (ch >> 3);
        int s = ch & 7;
        *(half8v*)(outp + rowb + j * 64 + ((s ^ (j & 7)) << 3)) = v;
      }
    }
  }
}

// ---------------- fused Shift + S4D, one block per (b,h) -------------------
__global__ __launch_bounds__(256) void s4d_main(
    const half_t* __restrict__ kimg, const half_t* __restrict__ vimg,
    const half_t* __restrict__ T1t, const half_t* __restrict__ T2t,
    const half_t* __restrict__ Vt, const half_t* __restrict__ Et,
    const half_t* __restrict__ Tt, const float* __restrict__ wt2,
    const float* __restrict__ shD, const float* __restrict__ s4D,
    const half_t* __restrict__ qbuf, float* __restrict__ outp) {
  __shared__ half_t kl[33 * 64];   // row 0 zeros; row 1+j = k chunk j
  __shared__ half_t vg[32 * 64];   // v, later G~ (f16)
  __shared__ half_t uh[32 * 64];   // u = v * shift(k)
  __shared__ half_t tabA[4096];    // T1 -> E
  __shared__ half_t tabB[4096];    // T2 -> T
  __shared__ half_t tabC[4096];    // V
  __shared__ float SG[32 * 66];    // S states / flat y
  // XCD swizzle: each XCD gets contiguous head range (tables L2-resident)
  int swz = (blockIdx.x & 7) * 512 + (blockIdx.x >> 3);
  int h = swz >> 3, bi = swz & 7;
  int bh = bi * 512 + h;
  int tid = threadIdx.x;
  int lane = tid & 63, wid = tid >> 6;
  int lrow = lane & 15, lg = lane >> 4;
  int mi = wid & 1, ri0 = wid >> 1;

  // ---- stage k, v, T1, T2, V via gload_lds (8 per wave) ----
  {
    size_t tb = (size_t)h * 4096;
    gload_lds16(kimg + (size_t)bh * 2048 + wid * 512 + lane * 8,
                kl + 64 + wid * 512);
    gload_lds16(vimg + (size_t)bh * 2048 + wid * 512 + lane * 8,
                vg + wid * 512);
#pragma unroll
    for (int i = 0; i < 2; i++) {
      int c = wid * 2 + i;
      gload_lds16(T1t + tb + c * 512 + lane * 8, tabA + c * 512);
      gload_lds16(T2t + tb + c * 512 + lane * 8, tabB + c * 512);
      gload_lds16(Vt + tb + c * 512 + lane * 8, tabC + c * 512);
    }
  }
  if (tid < 8) {
    half8v zz = {(_Float16)0, (_Float16)0, (_Float16)0, (_Float16)0,
                 (_Float16)0, (_Float16)0, (_Float16)0, (_Float16)0};
    *(half8v*)(kl + tid * 8) = zz;
  }
  float sDsh = shD[h];
  float sD4 = s4D[h];
  float wTr = wt2[h * 64 + 2 * (tid & 31)];
  float wTi = wt2[h * 64 + 2 * (tid & 31) + 1];
  asm volatile("s_waitcnt vmcnt(0) lgkmcnt(0)" ::: "memory");
  __builtin_amdgcn_s_barrier();
  __builtin_amdgcn_sched_barrier(0);

#define LDF(base, r, ks, key) \
  (*(const half8v*)((base) + (r) * 64 + (((ks) * 4 + lg) ^ (key)) * 8))

  floatx4 acc[2];
  // ---- shift: shift[j][r] = k_j @ T1' + k_{j-1} @ T2' ----
  acc[0] = (floatx4){0.f, 0.f, 0.f, 0.f};
  acc[1] = (floatx4){0.f, 0.f, 0.f, 0.f};
  {
    int jA = mi * 16 + lrow;
    int key1 = lrow & 7, key2 = (lrow + 7) & 7;
#pragma unroll
    for (int ks = 0; ks < 2; ks++) {
      half8v a1 = LDF(kl, 1 + jA, ks, key1);
      half8v a2 = LDF(kl, jA, ks, key2);
#pragma unroll
      for (int tt = 0; tt < 2; tt++) {
        int rb = (ri0 + tt * 2) * 16 + lrow;
        half8v b1 = LDF(tabA, rb, ks, lrow & 7);
        half8v b2 = LDF(tabB, rb, ks, lrow & 7);
        acc[tt] = __builtin_amdgcn_mfma_f32_16x16x32_f16(a1, b1, acc[tt], 0, 0, 0);
        acc[tt] = __builtin_amdgcn_mfma_f32_16x16x32_f16(a2, b2, acc[tt], 0, 0, 0);
      }
    }
  }
  // u = v * (shift + shD*k)
#pragma unroll
  for (int tt = 0; tt < 2; tt++) {
#pragma unroll
    for (int reg = 0; reg < 4; reg++) {
      int j = mi * 16 + 4 * lg + reg;
      int r = (ri0 + tt * 2) * 16 + lrow;
      int cph = (((r >> 3) ^ (j & 7)) << 3) + (r & 7);
      float kvv = (float)kl[(1 + j) * 64 + cph];
      float vvv = (float)vg[j * 64 + cph];
      uh[j * 64 + cph] = (half_t)(vvv * (acc[tt][reg] + sDsh * kvv));
    }
  }
  WAIT_LGKM_BAR();   // all shift reads of tabA/tabB complete past this point

  // ---- issue E,T stage into tabA,tabB (flies during S phase) ----
  {
    size_t tb = (size_t)h * 4096;
#pragma unroll
    for (int i = 0; i < 2; i++) {
      int c = wid * 2 + i;
      gload_lds16(Et + tb + c * 512 + lane * 8, tabA + c * 512);
      gload_lds16(Tt + tb + c * 512 + lane * 8, tabB + c * 512);
    }
  }

  // ---- S phase: S[j][m] = u_j @ V' ----
  acc[0] = (floatx4){0.f, 0.f, 0.f, 0.f};
  acc[1] = (floatx4){0.f, 0.f, 0.f, 0.f};
#pragma unroll
  for (int ks = 0; ks < 2; ks++) {
    half8v a = LDF(uh, mi * 16 + lrow, ks, lrow & 7);
#pragma unroll
    for (int tt = 0; tt < 2; tt++) {
      int rb = (ri0 + tt * 2) * 16 + lrow;
      half8v b = LDF(tabC, rb, ks, lrow & 7);
      acc[tt] = __builtin_amdgcn_mfma_f32_16x16x32_f16(a, b, acc[tt], 0, 0, 0);
    }
  }
#pragma unroll
  for (int tt = 0; tt < 2; tt++) {
    int ri = ri0 + tt * 2;
#pragma unroll
    for (int reg = 0; reg < 4; reg++) {
      int j = mi * 16 + 4 * lg + reg;
      SG[j * 66 + ri * 16 + lrow] = acc[tt][reg];
    }
  }
  // drain E,T gloads + S writes together
  asm volatile("s_waitcnt vmcnt(0) lgkmcnt(0)" ::: "memory");
  __builtin_amdgcn_s_barrier();
  __builtin_amdgcn_sched_barrier(0);

  // ---- scan (thread n): emit f16 G_{j-1} directly into vg ----
  if (tid < 32) {
    int n = tid;
    float gr = 0.f, gi = 0.f;
#pragma unroll 4
    for (int j = 0; j < 32; j++) {
      float tr = SG[j * 66 + 2 * n], ti = SG[j * 66 + 2 * n + 1];
      half2v gp = {(half_t)gr, (half_t)gi};
      *(half2v*)(vg + j * 64 + (((n >> 2) ^ (j & 7)) << 3) + 2 * (n & 3)) = gp;
      float nr = wTr * gr - wTi * gi + tr;
      gi = wTr * gi + wTi * gr + ti;
      gr = nr;
    }
  }
  WAIT_LGKM_BAR();

  // ---- Y: Y[j][r] = G~_j @ E' + u_j @ T' ; y -> SG flat ----
  acc[0] = (floatx4){0.f, 0.f, 0.f, 0.f};
  acc[1] = (floatx4){0.f, 0.f, 0.f, 0.f};
#pragma unroll
  for (int ks = 0; ks < 2; ks++) {
    half8v ag = LDF(vg, mi * 16 + lrow, ks, lrow & 7);
    half8v au = LDF(uh, mi * 16 + lrow, ks, lrow & 7);
#pragma unroll
    for (int tt = 0; tt < 2; tt++) {
      int rb = (ri0 + tt * 2) * 16 + lrow;
      half8v be = LDF(tabA, rb, ks, lrow & 7);
      half8v bt = LDF(tabB, rb, ks, lrow & 7);
      acc[tt] = __builtin_amdgcn_mfma_f32_16x16x32_f16(ag, be, acc[tt], 0, 0, 0);
      acc[tt] = __builtin_amdgcn_mfma_f32_16x16x32_f16(au, bt, acc[tt], 0, 0, 0);
    }
  }
#pragma unroll
  for (int tt = 0; tt < 2; tt++) {
#pragma unroll
    for (int reg = 0; reg < 4; reg++) {
      int j = mi * 16 + 4 * lg + reg;
      int r = (ri0 + tt * 2) * 16 + lrow;
      int cph = (((r >> 3) ^ (j & 7)) << 3) + (r & 7);
      SG[j * 64 + r] = acc[tt][reg] + sD4 * (float)uh[j * 64 + cph];
    }
  }
  WAIT_LGKM_BAR();

  // ---- final coalesced pass: out = q * y ----
  {
    size_t base = (size_t)bh * 2048;
    half8v qv = *(const half8v*)(qbuf + base + tid * 8);
    float* op = outp + base;
    float4 o0, o1;
    o0.x = (float)qv[0] * SG[tid * 8 + 0];
    o0.y = (float)qv[1] * SG[tid * 8 + 1];
    o0.z = (float)qv[2] * SG[tid * 8 + 2];
    o0.w = (float)qv[3] * SG[tid * 8 + 3];
    o1.x = (float)qv[4] * SG[tid * 8 + 4];
    o1.y = (float)qv[5] * SG[tid * 8 + 5];
    o1.z = (float)qv[6] * SG[tid * 8 + 6];
    o1.w = (float)qv[7] * SG[tid * 8 + 7];
    *(float4*)(op + tid * 8) = o0;
    *(float4*)(op + tid * 8 + 4) = o1;
  }
#undef LDF
}

// ---------------------------------------------------------------------------
extern "C" void kernel_launch(void* const* d_in, const int* in_sizes, int n_in,
                              void* d_out, int out_size, void* d_ws, size_t ws_size,
                              hipStream_t stream) {
  const float* x      = (const float*)d_in[0];
  const float* Wq     = (const float*)d_in[1];
  const float* bq     = (const float*)d_in[2];
  const float* Wk     = (const float*)d_in[3];
  const float* bk     = (const float*)d_in[4];
  const float* Wv     = (const float*)d_in[5];
  const float* bv     = (const float*)d_in[6];
  const float* shC    = (const float*)d_in[7];
  const float* shD    = (const float*)d_in[8];
  const float* log_dt = (const float*)d_in[9];
  const float* A_real = (const float*)d_in[10];
  const float* A_imag = (const float*)d_in[11];
  const float* C_re   = (const float*)d_in[12];
  const float* C_im   = (const float*)d_in[13];
  const float* s4D    = (const float*)d_in[14];
  float* out = (float*)d_out;
  half_t* wsh = (half_t*)d_ws;

  half_t* qbuf = wsh;                         // 8388608 halfs (linear)
  half_t* kbuf = wsh + 8388608;               // 8388608 (swizzled image)
  half_t* vbuf = wsh + 16777216;              // 8388608 (swizzled image)
  half_t* xT16 = wsh + 25165824;              // 8388608
  half_t* W16  = wsh + 33554432;              // 786432
  half_t* Vt   = wsh + 34340864;              // 2097152 (swizzled image)
  half_t* Et   = wsh + 36438016;              // 2097152
  half_t* Tt   = wsh + 38535168;              // 2097152
  half_t* T1t  = wsh + 40632320;              // 2097152
  half_t* T2t  = wsh + 42729472;              // 2097152
  float*  wt2  = (float*)(wsh + 44826624);    // 32768 f32

  prep<<<3072, 256, 0, stream>>>(x, Wq, Wk, Wv, log_dt, A_real, A_imag,
                                 C_re, C_im, shC, xT16, W16,
                                 Vt, Et, Tt, T1t, T2t, wt2);
  gemm_qkv<<<dim3(1536), 256, 0, stream>>>(xT16, W16, bq, bk, bv,
                                           qbuf, kbuf, vbuf);
  s4d_main<<<4096, 256, 0, stream>>>(kbuf, vbuf, T1t, T2t, Vt, Et, Tt,
                                     wt2, shD, s4D, qbuf, out);
}